// Round 5
// baseline (196.649 us; speedup 1.0000x reference)
//
#include <hip/hip_runtime.h>

// MeanConv: out = mask * (1/7) * sum_{k in 3,5,..,15} boxmean_k(x), edge padding.
// Per-tile 2D integral image in LDS; each box sum = 4-corner difference.
//   P1: stage+row-prefix fused (float4 global loads, 4-lane shfl fixup).
//   P2: column prefix, 4 row-segments per column, register prefix + shfl fixup.
//   P3: 8 px/thread, span-merged corner reads (read2-friendly scalar form).
// 512 threads/block on the same 64x64 tile: 27.1KB LDS -> 4 blocks x 8 waves
// = 32 waves/CU (HW cap) vs 20 at 256 threads. Kernel is latency-bound
// (VALU 20%, HBM 26%, LDS ~35%, nothing saturated) -> occupancy is the lever.
// __launch_bounds__(512,8) pins VGPR<=64 so 4 blocks/CU actually fit.
// Phase-3 lane map: ty=(l>>3)+8w, B0=8*(l&7): lanes 0..7 = one contiguous
// 256B output row segment (coalesced); LDS = 2 lanes/bank (free 2-way).

#define TILE   64
#define HALO   7
#define LHX    8            // left halo (8 for float4 alignment)
#define NCOL   80           // staged cols: c0-8 .. c0+71
#define NROW   78           // staged rows: r0-7 .. r0+70
#define PSTR   83           // odd; 19 mod 32 -> conflict-free/2-way patterns
#define PROWSA 81           // rows 0..78 used + 2 slack (safe predicated reads)
#define HH     4096
#define WW     4096

__global__ __launch_bounds__(512, 8) void meanconv_kernel(
    const float* __restrict__ x, const float* __restrict__ mask,
    float* __restrict__ out)
{
    __shared__ float P[PROWSA * PSTR];   // 81*83*4 = 26892 B
    const int tid = threadIdx.x;
    const int c0  = blockIdx.x * TILE;
    const int r0  = blockIdx.y * TILE;

    // zero row 0 (cols 0..80); rows 1..78 written below, no race
    if (tid < 81) P[tid] = 0.0f;

    const bool xint = (c0 >= LHX) && (c0 - LHX + NCOL <= WW);

    // ---- phase 1: fused global stage + row-wise inclusive prefix ----
    for (int idx = tid; idx < NROW * 4; idx += 512) {
        const int lr  = idx >> 2;        // staged row 0..77
        const int s   = idx & 3;         // 20-col segment within the row
        const int gr  = min(max(r0 + lr - HALO, 0), HH - 1);
        const int gc0 = c0 - LHX + 20 * s;
        float v[20];
        if (xint) {
            const float* src = &x[(size_t)gr * WW + gc0];
            #pragma unroll
            for (int q = 0; q < 5; ++q) {
                const float4 t = *(const float4*)(src + 4 * q);
                v[4*q+0] = t.x; v[4*q+1] = t.y; v[4*q+2] = t.z; v[4*q+3] = t.w;
            }
        } else {
            #pragma unroll
            for (int i = 0; i < 20; ++i) {
                const int gc = min(max(gc0 + i, 0), WW - 1);
                v[i] = x[(size_t)gr * WW + gc];
            }
        }
        #pragma unroll
        for (int i = 1; i < 20; ++i) v[i] += v[i - 1];
        // 4-lane (one row) exclusive prefix of segment totals
        const float tot = v[19];
        float sum = tot;
        float u = __shfl_up(sum, 1, 4); if (s >= 1) sum += u;
        u       = __shfl_up(sum, 2, 4); if (s >= 2) sum += u;
        const float off = sum - tot;
        float* dst = &P[(lr + 1) * PSTR + 1 + 20 * s];
        #pragma unroll
        for (int i = 0; i < 20; ++i) dst[i] = v[i] + off;
    }
    __syncthreads();

    // ---- phase 2: column-wise inclusive prefix over rows 1..78 ----
    for (int idx = tid; idx < 80 * 4; idx += 512) {
        const int c  = (idx >> 2) + 1;   // col 1..80
        const int s  = idx & 3;          // row segment (20,20,20,18)
        const int rs = 1 + 20 * s;
        float v[20];
        float run = 0.0f;
        #pragma unroll
        for (int i = 0; i < 20; ++i) {
            const int r = rs + i;
            float t = P[r * PSTR + c];   // rows 79,80 are in-bounds slack
            t = (r < 79) ? t : 0.0f;     // zero out slack garbage
            run += t; v[i] = run;
        }
        const float tot = run;
        float sum = tot;
        float u = __shfl_up(sum, 1, 4); if (s >= 1) sum += u;
        u       = __shfl_up(sum, 2, 4); if (s >= 2) sum += u;
        const float off = sum - tot;
        #pragma unroll
        for (int i = 0; i < 20; ++i) {
            const int r = rs + i;
            if (r < 79) P[r * PSTR + c] = v[i] + off;
        }
    }
    __syncthreads();
    // P[a][b] = sum of staged[row < a][col < b].

    // ---- phase 3: 8 consecutive-x pixels per thread, one row each ----
    // lane l=tid&63, wave w=tid>>6: row ty=(l>>3)+8w, col group B0=8*(l&7).
    const int l  = tid & 63;
    const int w_ = tid >> 6;
    const int ty = (l >> 3) + 8 * w_;    // 0..63
    const int B0 = 8 * (l & 7);
    const int A  = ty + HALO;            // staged row of the pixel
    float a[8];
    #pragma unroll
    for (int i = 0; i < 8; ++i) a[i] = 0.0f;

    #pragma unroll
    for (int p = 1; p <= 7; ++p) {
        const int   k = 2 * p + 1;
        const float wgt = 1.0f / (7.0f * (float)(k * k));
        const int   W = 9 + 2 * p;       // span cols [B0+8-p, B0+16+p]
        const float* rT = &P[(A - p)     * PSTR + B0 + LHX - p];
        const float* rB = &P[(A + p + 1) * PSTR + B0 + LHX - p];
        float D[23];
        #pragma unroll
        for (int q = 0; q < W; ++q) D[q] = rB[q] - rT[q];
        #pragma unroll
        for (int i = 0; i < 8; ++i)
            a[i] += wgt * (D[k + i] - D[i]);
    }

    const int gr = r0 + ty, gc = c0 + B0;
    const float* mrow = &mask[(size_t)gr * WW + gc];
    float*       orow = &out[(size_t)gr * WW + gc];
    const float4 m0 = *(const float4*)(mrow);
    const float4 m1 = *(const float4*)(mrow + 4);
    float4 o0, o1;
    o0.x = a[0] * m0.x; o0.y = a[1] * m0.y; o0.z = a[2] * m0.z; o0.w = a[3] * m0.w;
    o1.x = a[4] * m1.x; o1.y = a[5] * m1.y; o1.z = a[6] * m1.z; o1.w = a[7] * m1.w;
    *(float4*)(orow)     = o0;
    *(float4*)(orow + 4) = o1;
}

extern "C" void kernel_launch(void* const* d_in, const int* in_sizes, int n_in,
                              void* d_out, int out_size, void* d_ws, size_t ws_size,
                              hipStream_t stream) {
    const float* x    = (const float*)d_in[0];
    const float* mask = (const float*)d_in[1];
    float*       out  = (float*)d_out;
    dim3 grid(WW / TILE, HH / TILE);
    meanconv_kernel<<<grid, 512, 0, stream>>>(x, mask, out);
}

// Round 10
// 194.123 us; speedup vs baseline: 1.0130x; 1.0130x over previous
//
#include <hip/hip_runtime.h>

// MeanConv: out = mask * (1/7) * sum_{k in 3,5,..,15} boxmean_k(x), edge padding.
// Per-tile 2D integral image in LDS; each box sum = 4-corner difference.
//   P1: stage+row-prefix fused (float4 global loads, 4-lane shfl fixup).
//   P2: column prefix, 4 row-segments per column, register prefix + shfl fixup.
//   P3: 16 px/thread, span-merged corner reads; mask loads issued at top of
//       P3 so HBM latency hides under the 7-scale LDS span loop.
// NEW: 2 vertical tiles per block, software-pipelined (T14): tile-1's x-loads
// are issued into registers right after tile-0's P2 barrier and consumed in
// tile-1's P1 — their HBM latency hides under tile-0's entire P3. Rationale:
// measured phase convoy — LDS-pipe ~50us + HBM ~27us serialize to ~78us
// (VALU 20%, HBM 26%, occ-doubling neutral -> no pipe saturated; phases
// alternate bursts). Overlapping fetch with P3 attacks the serial sum.
// 256 threads (measured best; 512/VGPR-pin regressed), PSTR 83 (2-way-free).

#define TILE   64
#define HALO   7
#define LHX    8            // left halo (8 for float4 alignment)
#define NCOL   80           // staged cols: c0-8 .. c0+71
#define NROW   78           // staged rows: r0-7 .. r0+70
#define PSTR   83           // odd; 19 mod 32 -> conflict-free/2-way patterns
#define PROWSA 81           // rows 0..78 used + 2 slack (safe predicated reads)
#define HH     4096
#define WW     4096

__global__ __launch_bounds__(256) void meanconv_kernel(
    const float* __restrict__ x, const float* __restrict__ mask,
    float* __restrict__ out)
{
    __shared__ float P[PROWSA * PSTR];   // 81*83*4 = 26892 B
    const int tid    = threadIdx.x;
    const int c0     = blockIdx.x * TILE;
    const int r0base = blockIdx.y * (2 * TILE);

    // zero row 0 (cols 0..80); never rewritten, stays zero for both tiles
    if (tid < 81) P[tid] = 0.0f;

    const bool xint = (c0 >= LHX) && (c0 - LHX + NCOL <= WW);

    // segment loader: staged row lr = idx>>2, 20-col segment s = idx&3
    auto load_seg = [&](int r0, int idx, float* v) {
        const int lr  = idx >> 2;
        const int s   = idx & 3;
        const int gr  = min(max(r0 + lr - HALO, 0), HH - 1);
        const int gc0 = c0 - LHX + 20 * s;
        if (xint) {
            const float* src = &x[(size_t)gr * WW + gc0];
            #pragma unroll
            for (int q = 0; q < 5; ++q) {
                const float4 t = *(const float4*)(src + 4 * q);
                v[4*q+0] = t.x; v[4*q+1] = t.y; v[4*q+2] = t.z; v[4*q+3] = t.w;
            }
        } else {
            #pragma unroll
            for (int i = 0; i < 20; ++i) {
                const int gc = min(max(gc0 + i, 0), WW - 1);
                v[i] = x[(size_t)gr * WW + gc];
            }
        }
    };
    // prefix one segment + 4-lane shfl fixup + LDS write
    auto prefix_write = [&](int idx, float* v) {
        const int lr = idx >> 2;
        const int s  = idx & 3;
        #pragma unroll
        for (int i = 1; i < 20; ++i) v[i] += v[i - 1];
        const float tot = v[19];
        float sum = tot;
        float u = __shfl_up(sum, 1, 4); if (s >= 1) sum += u;
        u       = __shfl_up(sum, 2, 4); if (s >= 2) sum += u;
        const float off = sum - tot;
        float* dst = &P[(lr + 1) * PSTR + 1 + 20 * s];
        #pragma unroll
        for (int i = 0; i < 20; ++i) dst[i] = v[i] + off;
    };

    // P3 thread mapping (16 px/thread): col group g, tile row ty
    const int g  = tid & 3;
    const int ty = tid >> 2;             // 0..63
    const int B0 = 16 * g;
    const int A  = ty + HALO;            // staged row of the pixel

    float v[20];                          // pipelined x-prefetch registers
    load_seg(r0base, tid, v);             // tile-0 segment-0 prefetch

    #pragma unroll
    for (int t = 0; t < 2; ++t) {
        const int r0 = r0base + TILE * t;

        // ---- phase 1: prefix + write (segment 0 from prefetch regs) ----
        prefix_write(tid, v);
        if (tid < 56) {                   // leftover segments 256..311
            float w2[20];
            load_seg(r0, tid + 256, w2);
            prefix_write(tid + 256, w2);
        }
        __syncthreads();

        // ---- phase 2: column-wise inclusive prefix over rows 1..78 ----
        for (int idx = tid; idx < 80 * 4; idx += 256) {
            const int c  = (idx >> 2) + 1;   // col 1..80
            const int s  = idx & 3;          // row segment (20,20,20,18)
            const int rs = 1 + 20 * s;
            float vv[20];
            float run = 0.0f;
            #pragma unroll
            for (int i = 0; i < 20; ++i) {
                const int r = rs + i;
                float tt = P[r * PSTR + c];  // rows 79,80 in-bounds slack
                tt = (r < 79) ? tt : 0.0f;
                run += tt; vv[i] = run;
            }
            const float tot = run;
            float sum = tot;
            float u = __shfl_up(sum, 1, 4); if (s >= 1) sum += u;
            u       = __shfl_up(sum, 2, 4); if (s >= 2) sum += u;
            const float off = sum - tot;
            #pragma unroll
            for (int i = 0; i < 20; ++i) {
                const int r = rs + i;
                if (r < 79) P[r * PSTR + c] = vv[i] + off;
            }
        }
        __syncthreads();
        // P[a][b] = sum of staged[row < a][col < b].

        // ---- pipeline: issue next tile's x-loads before P3 ----
        if (t == 0) load_seg(r0base + TILE, tid, v);

        // ---- phase 3: 16 px/thread; mask issued early, spans from LDS ----
        const int gr = r0 + ty, gc = c0 + B0;
        const float* mrow = &mask[(size_t)gr * WW + gc];
        const float4 m0 = *(const float4*)(mrow);
        const float4 m1 = *(const float4*)(mrow + 4);
        const float4 m2 = *(const float4*)(mrow + 8);
        const float4 m3 = *(const float4*)(mrow + 12);

        float a[16];
        #pragma unroll
        for (int i = 0; i < 16; ++i) a[i] = 0.0f;

        #pragma unroll
        for (int p = 1; p <= 7; ++p) {
            const int   k = 2 * p + 1;
            const float wgt = 1.0f / (7.0f * (float)(k * k));
            const int   W = 17 + 2 * p;  // span cols [B0+8-p, B0+24+p]
            const float* rT = &P[(A - p)     * PSTR + B0 + LHX - p];
            const float* rB = &P[(A + p + 1) * PSTR + B0 + LHX - p];
            float D[31];
            #pragma unroll
            for (int q = 0; q < W; ++q) D[q] = rB[q] - rT[q];
            #pragma unroll
            for (int i = 0; i < 16; ++i)
                a[i] += wgt * (D[k + i] - D[i]);
        }
        __syncthreads();                 // P3 LDS reads done; safe to rewrite P

        float* orow = &out[(size_t)gr * WW + gc];
        float4 o;
        o.x = a[0]*m0.x;  o.y = a[1]*m0.y;  o.z = a[2]*m0.z;  o.w = a[3]*m0.w;
        *(float4*)(orow)      = o;
        o.x = a[4]*m1.x;  o.y = a[5]*m1.y;  o.z = a[6]*m1.z;  o.w = a[7]*m1.w;
        *(float4*)(orow + 4)  = o;
        o.x = a[8]*m2.x;  o.y = a[9]*m2.y;  o.z = a[10]*m2.z; o.w = a[11]*m2.w;
        *(float4*)(orow + 8)  = o;
        o.x = a[12]*m3.x; o.y = a[13]*m3.y; o.z = a[14]*m3.z; o.w = a[15]*m3.w;
        *(float4*)(orow + 12) = o;
    }
}

extern "C" void kernel_launch(void* const* d_in, const int* in_sizes, int n_in,
                              void* d_out, int out_size, void* d_ws, size_t ws_size,
                              hipStream_t stream) {
    const float* x    = (const float*)d_in[0];
    const float* mask = (const float*)d_in[1];
    float*       out  = (float*)d_out;
    dim3 grid(WW / TILE, HH / (2 * TILE));
    meanconv_kernel<<<grid, 256, 0, stream>>>(x, mask, out);
}

// Round 14
// 185.599 us; speedup vs baseline: 1.0595x; 1.0459x over previous
//
#include <hip/hip_runtime.h>

// MeanConv: out = mask * (1/7) * sum_{k in 3,5,..,15} boxmean_k(x), edge padding.
// Per-tile 2D integral image in LDS; each box sum = 4-corner difference.
// ALL LDS phases b128-clean (this round's change):
//   Layout: P'[r][c] = prefix[r][c+1] (col 0 of the old layout was never
//   read), PSTR=84 -> every row 16B-aligned, row stride 21 quads (odd).
//   P1: stage + row-prefix; writes 5x ds_write_b128 per 20-word segment
//       (quad-spread: 8 lanes/quad = conflict-free optimum, hand-audited).
//   P2: scalar column prefix, banks 2-way (free).
//   P3: 16 px/thread; per scale read both corner rows as ALIGNED float4
//       windows (98 ds_read_b128/thread, 8 lanes/quad). ~3 cy/word vs
//       ~4 cy/word for the read2 form -> ~-17% LDS-pipe cycles.
// r3 failed this idea because PSTR=84 + unshifted layout made P1's scalar
// writes 8-way conflicted (+1e7 conflict cycles). The column shift fixes P1
// structurally. r10's 2-tile pipeline reverted: VGPR 112 halved TLP (-42%).
// Single tile, 256 threads, VGPR target ~56 (ridge: r4 ILP-dead @28,
// r10 TLP-dead @112, best @48-64).

#define TILE   64
#define HALO   7
#define LHX    8            // left halo in x (8 for float4 global alignment)
#define NCOL   80           // staged cols: c0-8 .. c0+71 (P' col = old col-1)
#define NROW   78           // staged rows: r0-7 .. r0+70
#define PSTR   84           // 16B-aligned rows; 21 quads (odd) -> even quad spread
#define PROWSA 81           // rows 0..78 used + 2 slack (safe predicated reads)
#define HH     4096
#define WW     4096

__global__ __launch_bounds__(256) void meanconv_kernel(
    const float* __restrict__ x, const float* __restrict__ mask,
    float* __restrict__ out)
{
    __shared__ float P[PROWSA * PSTR];   // 81*84*4 = 27216 B -> 6 blocks/CU
    const int tid = threadIdx.x;
    const int c0  = blockIdx.x * TILE;
    const int r0  = blockIdx.y * TILE;

    // zero row 0 (cols 0..83); rows 1..78 written below, no race
    if (tid < 84) P[tid] = 0.0f;

    const bool xint = (c0 >= LHX) && (c0 - LHX + NCOL <= WW);

    // ---- phase 1: fused global stage + row-wise inclusive prefix ----
    // P'[lr+1][20s+i] = prefix over staged cols 0..20s+i (old cols 1..80
    // shifted to 0..79). 16B-aligned b128 writes.
    for (int idx = tid; idx < NROW * 4; idx += 256) {
        const int lr  = idx >> 2;        // staged row 0..77
        const int s   = idx & 3;         // 20-col segment within the row
        const int gr  = min(max(r0 + lr - HALO, 0), HH - 1);
        const int gc0 = c0 - LHX + 20 * s;
        float v[20];
        if (xint) {
            const float* src = &x[(size_t)gr * WW + gc0];
            #pragma unroll
            for (int q = 0; q < 5; ++q) {
                const float4 t = *(const float4*)(src + 4 * q);
                v[4*q+0] = t.x; v[4*q+1] = t.y; v[4*q+2] = t.z; v[4*q+3] = t.w;
            }
        } else {
            #pragma unroll
            for (int i = 0; i < 20; ++i) {
                const int gc = min(max(gc0 + i, 0), WW - 1);
                v[i] = x[(size_t)gr * WW + gc];
            }
        }
        #pragma unroll
        for (int i = 1; i < 20; ++i) v[i] += v[i - 1];
        // 4-lane (one row) exclusive prefix of segment totals
        const float tot = v[19];
        float sum = tot;
        float u = __shfl_up(sum, 1, 4); if (s >= 1) sum += u;
        u       = __shfl_up(sum, 2, 4); if (s >= 2) sum += u;
        const float off = sum - tot;
        float* dst = &P[(lr + 1) * PSTR + 20 * s];   // 16B-aligned
        #pragma unroll
        for (int q = 0; q < 5; ++q) {
            float4 o4;
            o4.x = v[4*q+0] + off;
            o4.y = v[4*q+1] + off;
            o4.z = v[4*q+2] + off;
            o4.w = v[4*q+3] + off;
            *(float4*)(dst + 4 * q) = o4;
        }
    }
    __syncthreads();

    // ---- phase 2: column-wise inclusive prefix over rows 1..78 ----
    for (int idx = tid; idx < 80 * 4; idx += 256) {
        const int c  = idx >> 2;         // col 0..79 (shifted layout)
        const int s  = idx & 3;          // row segment (20,20,20,18)
        const int rs = 1 + 20 * s;
        float v[20];
        float run = 0.0f;
        #pragma unroll
        for (int i = 0; i < 20; ++i) {
            const int r = rs + i;
            float t = P[r * PSTR + c];   // rows 79,80 are in-bounds slack
            t = (r < 79) ? t : 0.0f;     // zero out slack garbage
            run += t; v[i] = run;
        }
        const float tot = run;
        float sum = tot;
        float u = __shfl_up(sum, 1, 4); if (s >= 1) sum += u;
        u       = __shfl_up(sum, 2, 4); if (s >= 2) sum += u;
        const float off = sum - tot;
        #pragma unroll
        for (int i = 0; i < 20; ++i) {
            const int r = rs + i;
            if (r < 79) P[r * PSTR + c] = v[i] + off;
        }
    }
    __syncthreads();
    // P'[a][b] = sum of staged[row < a][col <= b].

    // ---- phase 3: 16 consecutive-x pixels per thread, one row each ----
    // Corner cols in P': cl' = B0+7-p, cr' = cl'+k. Aligned window from
    // CS = (7-p)&~3; D = rB - rT over the window; a[i] += w*(D[o+k+i]-D[o+i]).
    const int g  = tid & 3;
    const int ty = tid >> 2;             // 0..63
    const int B0 = 16 * g;
    const int A  = ty + HALO;            // staged row of the pixel
    float a[16];
    #pragma unroll
    for (int i = 0; i < 16; ++i) a[i] = 0.0f;

    #pragma unroll
    for (int p = 1; p <= 7; ++p) {
        const int   k   = 2 * p + 1;
        const float wgt = 1.0f / (7.0f * (float)(k * k));
        const int   CS  = (7 - p) & ~3;           // 4,4,4,0,0,0,0
        const int   NR  = (24 + p - CS + 3) >> 2; // b128s: 6,6,6,7,8,8,8
        const int   o   = 7 - p - CS;             // cl' offset in window
        const float* rT = &P[(A - p)     * PSTR + B0 + CS];
        const float* rB = &P[(A + p + 1) * PSTR + B0 + CS];
        float D[32];
        #pragma unroll
        for (int q = 0; q < NR; ++q) {
            const float4 tq = *(const float4*)(rT + 4 * q);
            const float4 bq = *(const float4*)(rB + 4 * q);
            D[4*q+0] = bq.x - tq.x;
            D[4*q+1] = bq.y - tq.y;
            D[4*q+2] = bq.z - tq.z;
            D[4*q+3] = bq.w - tq.w;
        }
        #pragma unroll
        for (int i = 0; i < 16; ++i)
            a[i] += wgt * (D[o + k + i] - D[o + i]);
    }

    const int gr = r0 + ty, gc = c0 + B0;
    const float* mrow = &mask[(size_t)gr * WW + gc];
    float*       orow = &out[(size_t)gr * WW + gc];
    #pragma unroll
    for (int q = 0; q < 4; ++q) {
        const float4 m = *(const float4*)(mrow + 4 * q);
        float4 o4;
        o4.x = a[4*q+0] * m.x;
        o4.y = a[4*q+1] * m.y;
        o4.z = a[4*q+2] * m.z;
        o4.w = a[4*q+3] * m.w;
        *(float4*)(orow + 4 * q) = o4;
    }
}

extern "C" void kernel_launch(void* const* d_in, const int* in_sizes, int n_in,
                              void* d_out, int out_size, void* d_ws, size_t ws_size,
                              hipStream_t stream) {
    const float* x    = (const float*)d_in[0];
    const float* mask = (const float*)d_in[1];
    float*       out  = (float*)d_out;
    dim3 grid(WW / TILE, HH / TILE);
    meanconv_kernel<<<grid, 256, 0, stream>>>(x, mask, out);
}